// Round 7
// baseline (334.525 us; speedup 1.0000x reference)
//
#include <hip/hip_runtime.h>
#include <hip/hip_bf16.h>

#define IN_CH 4096
#define OUT_CH 11008
#define QBLK 64

#define BM 128
#define BN 64
#define BK 64
#define KCHUNKS (IN_CH / BK)            // 64
#define KSPLIT 4
#define SPLIT_CHUNKS (KCHUNKS / KSPLIT) // 16
#define NTILES (OUT_CH / BN)            // 172
#define XCONV_BLOCKS 16

typedef short bf16x8 __attribute__((ext_vector_type(8)));
typedef float f32x4 __attribute__((ext_vector_type(4)));
typedef unsigned int u32x2 __attribute__((ext_vector_type(2)));

__device__ inline unsigned short f2bf(float f) {
    union { __hip_bfloat16 h; unsigned short u; } cv;
    cv.h = __float2bfloat16(f);
    return cv.u;
}

// ---------------------------------------------------------------------------
// Kernel 1: LPBQ quantize of weight -> BIASED uint8 (q+8, so GEMM can use
// v_cvt_f32_ubyte) + fp32 s1r transposed [kblock][row].
// Blocks [OUT_CH, OUT_CH+16) convert x -> bf16 (plain layout — the GEMM now
// reads A fragments straight from global, no LDS, no swizzle needed).
// ---------------------------------------------------------------------------
__global__ __launch_bounds__(256) void quant_kernel(
        const float* __restrict__ w, const float* __restrict__ x,
        unsigned char* __restrict__ wq, float* __restrict__ s1rT,
        unsigned short* __restrict__ xq) {
    const int tid = threadIdx.x;

    if (blockIdx.x >= OUT_CH) {
        // ---- x fp32 -> bf16 (131072 float4) ----
        const int bx = blockIdx.x - OUT_CH;
        const float4* x4 = (const float4*)x;
        for (int it = 0; it < 32; ++it) {
            const int g = bx * 8192 + it * 256 + tid;
            float4 v = x4[g];
            ushort4 o;
            o.x = f2bf(v.x); o.y = f2bf(v.y); o.z = f2bf(v.z); o.w = f2bf(v.w);
            ((ushort4*)xq)[g] = o;
        }
        return;
    }

    const int row = blockIdx.x;
    const float* wrow = w + (size_t)row * IN_CH;
    unsigned char* orow = wq + (size_t)row * IN_CH;

    __shared__ float s1_lds[64];   // pass A: s1; after pass B: s1r
    float4 v[4];
    const int lane16 = tid & 15;

    // Pass A: per-64-block max|.| -> s1 (16 lanes per quant-block)
    for (int p = 0; p < 4; ++p) {
        v[p] = ((const float4*)wrow)[p * 256 + tid];
        float m = fmaxf(fmaxf(fabsf(v[p].x), fabsf(v[p].y)),
                        fmaxf(fabsf(v[p].z), fabsf(v[p].w)));
        m = fmaxf(m, __shfl_xor(m, 1));
        m = fmaxf(m, __shfl_xor(m, 2));
        m = fmaxf(m, __shfl_xor(m, 4));
        m = fmaxf(m, __shfl_xor(m, 8));
        if (lane16 == 0)
            s1_lds[p * 16 + (tid >> 4)] = fmaxf(m * (1.0f / 7.0f), 1e-8f);
    }
    __syncthreads();

    // Pass B: s2 = clip(max_b s1 / 15, 1e-8); s1r = clip(rint(s1/s2),0,15)*s2
    if (tid < 64) {
        float s1 = s1_lds[tid];
        float m = s1;
        m = fmaxf(m, __shfl_xor(m, 1));
        m = fmaxf(m, __shfl_xor(m, 2));
        m = fmaxf(m, __shfl_xor(m, 4));
        m = fmaxf(m, __shfl_xor(m, 8));
        m = fmaxf(m, __shfl_xor(m, 16));
        m = fmaxf(m, __shfl_xor(m, 32));
        const float s2 = fmaxf(m * (1.0f / 15.0f), 1e-8f);
        const float s1q = fminf(fmaxf(rintf(s1 / s2), 0.0f), 15.0f);
        const float s1r = s1q * s2;
        s1_lds[tid] = s1r;
        s1rT[(size_t)tid * OUT_CH + row] = s1r;   // transposed scale store
    }
    __syncthreads();

    // Pass C: wq = clip(rint(w / s1r), -8, 7) + 8, stored uint8
    for (int p = 0; p < 4; ++p) {
        const float s1r = s1_lds[p * 16 + (tid >> 4)];
        uchar4 o;
        o.x = (unsigned char)(int)(fminf(fmaxf(rintf(v[p].x / s1r), -8.0f), 7.0f) + 8.0f);
        o.y = (unsigned char)(int)(fminf(fmaxf(rintf(v[p].y / s1r), -8.0f), 7.0f) + 8.0f);
        o.z = (unsigned char)(int)(fminf(fmaxf(rintf(v[p].z / s1r), -8.0f), 7.0f) + 8.0f);
        o.w = (unsigned char)(int)(fminf(fmaxf(rintf(v[p].w / s1r), -8.0f), 7.0f) + 8.0f);
        ((uchar4*)orow)[p * 256 + tid] = o;
    }
}

// ---------------------------------------------------------------------------
// Kernel 2: barrier-free register-direct K-split GEMM.
// No LDS. Each wave owns a 64x32 output patch; MFMA fragments are loaded
// straight from global (A: 1 MB bf16, L2-hot; B: 45 MB biased-uint8, L3-hot)
// and B is dequantized in-register: fma(u, s1, -8*s1) = round(q*s1), bit-
// identical to the materialized-bf16 path. Register ping-pong prefetch,
// distance 1; zero __syncthreads in the K-loop.
// ---------------------------------------------------------------------------
struct Chunk {
    bf16x8 a[8];   // [i*2+kk] : A[wm*64+i*16+lane15][kc*64+kk*32+quad*8 ..+8]
    u32x2 b[4];    // [j*2+kk] : 8 biased-uint8 of B, same k window
    float s[2];    // s1r for the two j row-groups
};

__device__ inline void load_chunk(int kc, const unsigned short* __restrict__ Abase,
                                  const unsigned char* __restrict__ Bbase,
                                  const float* __restrict__ s1rT, int srow,
                                  Chunk& c) {
#pragma unroll
    for (int i = 0; i < 4; ++i)
#pragma unroll
        for (int kk = 0; kk < 2; ++kk)
            c.a[i * 2 + kk] =
                *(const bf16x8*)(Abase + (size_t)i * 16 * IN_CH + kc * 64 + kk * 32);
#pragma unroll
    for (int j = 0; j < 2; ++j)
#pragma unroll
        for (int kk = 0; kk < 2; ++kk)
            c.b[j * 2 + kk] =
                *(const u32x2*)(Bbase + (size_t)j * 16 * IN_CH + kc * 64 + kk * 32);
#pragma unroll
    for (int j = 0; j < 2; ++j)
        c.s[j] = s1rT[(size_t)kc * OUT_CH + srow + j * 16];
}

__device__ inline bf16x8 dq8(u32x2 u, float s1, float m8) {
    bf16x8 r;
#pragma unroll
    for (int h = 0; h < 2; ++h) {
        const unsigned int d = u[h];
        r[h * 4 + 0] = (short)f2bf(__builtin_fmaf((float)((d >> 0) & 0xffu), s1, m8));
        r[h * 4 + 1] = (short)f2bf(__builtin_fmaf((float)((d >> 8) & 0xffu), s1, m8));
        r[h * 4 + 2] = (short)f2bf(__builtin_fmaf((float)((d >> 16) & 0xffu), s1, m8));
        r[h * 4 + 3] = (short)f2bf(__builtin_fmaf((float)((d >> 24) & 0xffu), s1, m8));
    }
    return r;
}

__device__ inline void compute_chunk(const Chunk& c, f32x4 acc[4][2]) {
    bf16x8 bq[4];
#pragma unroll
    for (int j = 0; j < 2; ++j) {
        const float m8 = -8.0f * c.s[j];
#pragma unroll
        for (int kk = 0; kk < 2; ++kk)
            bq[j * 2 + kk] = dq8(c.b[j * 2 + kk], c.s[j], m8);
    }
#pragma unroll
    for (int kk = 0; kk < 2; ++kk)
#pragma unroll
        for (int i = 0; i < 4; ++i)
#pragma unroll
            for (int j = 0; j < 2; ++j)
                acc[i][j] = __builtin_amdgcn_mfma_f32_16x16x32_bf16(
                    c.a[i * 2 + kk], bq[j * 2 + kk], acc[i][j], 0, 0, 0);
}

__global__ __launch_bounds__(256) void gemm_kernel(
        const unsigned short* __restrict__ A, const unsigned char* __restrict__ WQ,
        const float* __restrict__ s1rT, float* __restrict__ part) {
    const int tid = threadIdx.x;
    const int w = tid >> 6;
    const int l = tid & 63;
    const int wm = w >> 1;
    const int wn = w & 1;
    const int lane15 = l & 15;
    const int quad = l >> 4;
    const int n0 = blockIdx.x * BN;
    const int kc0 = blockIdx.y * SPLIT_CHUNKS;
    const int kcEnd = kc0 + SPLIT_CHUNKS;

    const unsigned short* Abase = A + (size_t)(wm * 64 + lane15) * IN_CH + quad * 8;
    const int srow = n0 + wn * 32 + lane15;
    const unsigned char* Bbase = WQ + (size_t)srow * IN_CH + quad * 8;

    f32x4 acc[4][2] = {};

    Chunk cur, nxt;
    load_chunk(kc0, Abase, Bbase, s1rT, srow, cur);

    // ping-pong, 2 chunks per iteration (SPLIT_CHUNKS is even)
    for (int kc = kc0; kc < kcEnd; kc += 2) {
        const int k1 = (kc + 1 < kcEnd) ? kc + 1 : kc;
        const int k2 = (kc + 2 < kcEnd) ? kc + 2 : k1;
        load_chunk(k1, Abase, Bbase, s1rT, srow, nxt);
        compute_chunk(cur, acc);
        load_chunk(k2, Abase, Bbase, s1rT, srow, cur);
        compute_chunk(nxt, acc);
    }

    // ---- epilogue: partial store, C/D layout col=lane&15, row=quad*4+reg ----
    float* pbase = part + (size_t)blockIdx.y * BM * OUT_CH;
    const int m_base = wm * 64 + quad * 4;
    const int n_base = n0 + wn * 32 + lane15;
#pragma unroll
    for (int j = 0; j < 2; ++j) {
#pragma unroll
        for (int i = 0; i < 4; ++i) {
            const int m = m_base + i * 16;
            float* cp = pbase + (size_t)m * OUT_CH + n_base + j * 16;
            cp[0 * OUT_CH] = acc[i][j][0];
            cp[1 * OUT_CH] = acc[i][j][1];
            cp[2 * OUT_CH] = acc[i][j][2];
            cp[3 * OUT_CH] = acc[i][j][3];
        }
    }
}

// ---------------------------------------------------------------------------
// Kernel 3: reduce K-split partials + bias. Grid (11, 128) x 256 thr, float4.
// ---------------------------------------------------------------------------
__global__ __launch_bounds__(256) void reduce_kernel(
        const float* __restrict__ part, const float* __restrict__ bias,
        float* __restrict__ out) {
    const int m = blockIdx.y;
    const int x4 = blockIdx.x * 256 + threadIdx.x;
    if (x4 >= OUT_CH / 4) return;
    const size_t off = (size_t)m * OUT_CH + x4 * 4;

    float4 acc = ((const float4*)bias)[x4];
    for (int s = 0; s < KSPLIT; ++s) {
        float4 p = *(const float4*)(part + (size_t)s * BM * OUT_CH + off);
        acc.x += p.x; acc.y += p.y; acc.z += p.z; acc.w += p.w;
    }
    *(float4*)(out + off) = acc;
}

extern "C" void kernel_launch(void* const* d_in, const int* in_sizes, int n_in,
                              void* d_out, int out_size, void* d_ws, size_t ws_size,
                              hipStream_t stream) {
    const float* x = (const float*)d_in[0];       // (1,128,4096) fp32
    const float* weight = (const float*)d_in[1];  // (11008,4096) fp32
    const float* bias = (const float*)d_in[2];    // (11008,) fp32
    float* out = (float*)d_out;                   // (1,128,11008) fp32

    // workspace layout (16B-aligned slices)
    unsigned char* wsQ = (unsigned char*)d_ws;                    // 45.1 MB biased-uint8 w_q
    unsigned short* wsX = (unsigned short*)(wsQ + (size_t)OUT_CH * IN_CH); // 1 MB bf16 x
    float* wsS = (float*)(wsX + (size_t)BM * IN_CH);              // 2.8 MB s1r^T
    float* wsP = wsS + (size_t)QBLK * OUT_CH;                     // 22.5 MB partials

    quant_kernel<<<OUT_CH + XCONV_BLOCKS, 256, 0, stream>>>(weight, x, wsQ, wsS, wsX);
    gemm_kernel<<<dim3(NTILES, KSPLIT), 256, 0, stream>>>(wsX, wsQ, wsS, wsP);
    reduce_kernel<<<dim3((OUT_CH / 4 + 255) / 256, BM), 256, 0, stream>>>(
        wsP, bias, out);
}